// Round 16
// baseline (215.183 us; speedup 1.0000x reference)
//
#include <hip/hip_runtime.h>
#include <stdint.h>

#define BATCH 4
#define SEQ   2048
#define FDIM  512
#define NHEAD 8
#define HDIM  64
#define KNN   32

typedef unsigned int u32;
typedef unsigned long long u64;
typedef unsigned short u16;
typedef unsigned short bf16_t;

typedef __attribute__((ext_vector_type(8))) short short8;   // 8 bf16 = 4 VGPRs
typedef __attribute__((ext_vector_type(4))) float f32x4;

#define SF  ((size_t)SEQ * FDIM)            // 1,048,576 per-batch elements
#define BSF ((size_t)BATCH * SF)            // 4,194,304

#define GEMM_NB 768                         // 4 x 64 x 3
#define XBAR_NB 128                         // 4 batches x 32 chunks

__device__ __forceinline__ bf16_t f2bf(float f) {
    u32 x = __float_as_uint(f);
    return (bf16_t)((x + 0x7FFFu + ((x >> 16) & 1u)) >> 16);   // RNE
}
__device__ __forceinline__ float bf2f(bf16_t u) { return __uint_as_float(((u32)u) << 16); }
__device__ __forceinline__ void bf2x2(u32 p, float& a, float& b) {
    a = __uint_as_float(p << 16);          // element 2i (low u16)
    b = __uint_as_float(p & 0xFFFF0000u);  // element 2i+1 (high u16)
}
__device__ __forceinline__ u64 min_u64(u64 a, u64 b) { return a < b ? a : b; }
__device__ __forceinline__ u64 shfl_xor_u64(u64 v, int m) {
    int lo = __shfl_xor((int)(u32)v, m, 64);
    int hi = __shfl_xor((int)(u32)(v >> 32), m, 64);
    return (((u64)(u32)hi) << 32) | (u32)lo;
}

// ---------------------------------------------------------------------------
// Cast x / Wq / Wk / Wv (fp32) -> bf16, 8 elements/thread. grid.z selects.
// ---------------------------------------------------------------------------
__global__ __launch_bounds__(256) void cast_kernel(const float* __restrict__ x,
                                                   const float* __restrict__ wq,
                                                   const float* __restrict__ wk,
                                                   const float* __restrict__ wv,
                                                   bf16_t* __restrict__ xb,
                                                   bf16_t* __restrict__ wqb,
                                                   bf16_t* __restrict__ wkb,
                                                   bf16_t* __restrict__ wvb) {
    const int z = blockIdx.z;
    const float* src = (z == 0) ? x : (z == 1) ? wq : (z == 2) ? wk : wv;
    bf16_t* dst      = (z == 0) ? xb : (z == 1) ? wqb : (z == 2) ? wkb : wvb;
    const size_t cnt8 = (z == 0) ? (BSF / 8) : ((size_t)FDIM * FDIM / 8);
    size_t idx = (size_t)blockIdx.x * 256 + threadIdx.x;
    if (idx >= cnt8) return;
    const float4 a = ((const float4*)src)[idx * 2 + 0];
    const float4 b = ((const float4*)src)[idx * 2 + 1];
    uint4 o;
    o.x = (u32)f2bf(a.x) | ((u32)f2bf(a.y) << 16);
    o.y = (u32)f2bf(a.z) | ((u32)f2bf(a.w) << 16);
    o.z = (u32)f2bf(b.x) | ((u32)f2bf(b.y) << 16);
    o.w = (u32)f2bf(b.z) | ((u32)f2bf(b.w) << 16);
    ((uint4*)dst)[idx] = o;
}

// ---------------------------------------------------------------------------
// GEMM body (HW-validated r8..r15): 128x128 tile, BK=32, MFMA 16x16x32.
// ---------------------------------------------------------------------------
__device__ __forceinline__ void gemm_body(char* smem, int bid,
                                          const bf16_t* __restrict__ xb,
                                          const bf16_t* __restrict__ wqb,
                                          const bf16_t* __restrict__ wkb,
                                          const bf16_t* __restrict__ wvb,
                                          float* __restrict__ qout,
                                          bf16_t* __restrict__ kvout) {
    bf16_t* As = (bf16_t*)smem;
    bf16_t* Bs = As + 128 * 32;
    const int z  = bid >> 8;                  // 0..2
    const int bx = bid & 3;
    const int by = (bid >> 2) & 63;
    const bf16_t* W = (z == 0) ? wqb : (z == 1) ? wkb : wvb;
    const int tid  = threadIdx.x;
    const int wid  = tid >> 6, lane = tid & 63;
    const int m16  = lane & 15, quad = lane >> 4;
    const int wm   = (wid & 1) * 64;
    const int wn   = (wid >> 1) * 64;
    const int m0   = by * 128;
    const int n0   = bx * 128;

    const int sr = tid >> 2, sc = (tid & 3) * 8;
    const bf16_t* agp = xb + (size_t)(m0 + sr) * FDIM + sc;
    const bf16_t* bgp = W  + (size_t)(n0 + sr) * FDIM + sc;

    f32x4 acc[4][4];
#pragma unroll
    for (int i = 0; i < 4; ++i)
#pragma unroll
        for (int j = 0; j < 4; ++j) acc[i][j] = (f32x4){0.f, 0.f, 0.f, 0.f};

#pragma unroll 1
    for (int k0 = 0; k0 < FDIM; k0 += 32) {
        uint4 a0 = *(const uint4*)(agp + k0);
        uint4 a1 = *(const uint4*)(agp + (size_t)64 * FDIM + k0);
        uint4 b0 = *(const uint4*)(bgp + k0);
        uint4 b1 = *(const uint4*)(bgp + (size_t)64 * FDIM + k0);
        __syncthreads();
        *(uint4*)(As + sr * 32 + sc)        = a0;
        *(uint4*)(As + (sr + 64) * 32 + sc) = a1;
        *(uint4*)(Bs + sr * 32 + sc)        = b0;
        *(uint4*)(Bs + (sr + 64) * 32 + sc) = b1;
        __syncthreads();

        short8 af[4], bfr[4];
#pragma unroll
        for (int i = 0; i < 4; ++i)
            af[i] = *(const short8*)(As + (wm + i * 16 + m16) * 32 + quad * 8);
#pragma unroll
        for (int j = 0; j < 4; ++j)
            bfr[j] = *(const short8*)(Bs + (wn + j * 16 + m16) * 32 + quad * 8);
#pragma unroll
        for (int i = 0; i < 4; ++i)
#pragma unroll
            for (int j = 0; j < 4; ++j)
                acc[i][j] = __builtin_amdgcn_mfma_f32_16x16x32_bf16(af[i], bfr[j],
                                                                    acc[i][j], 0, 0, 0);
    }

    if (z == 0) {
#pragma unroll
        for (int i = 0; i < 4; ++i) {
            const int rowb = m0 + wm + i * 16 + quad * 4;
#pragma unroll
            for (int r = 0; r < 4; ++r) {
                float* orow = qout + (size_t)(rowb + r) * FDIM + n0 + wn + m16;
                orow[ 0] = acc[i][0][r]; orow[16] = acc[i][1][r];
                orow[32] = acc[i][2][r]; orow[48] = acc[i][3][r];
            }
        }
    } else {
        bf16_t* base = kvout + (size_t)(z - 1) * BSF;
#pragma unroll
        for (int i = 0; i < 4; ++i) {
            const int rowb = m0 + wm + i * 16 + quad * 4;
#pragma unroll
            for (int r = 0; r < 4; ++r) {
                bf16_t* orow = base + (size_t)(rowb + r) * FDIM + n0 + wn + m16;
                orow[ 0] = f2bf(acc[i][0][r]); orow[16] = f2bf(acc[i][1][r]);
                orow[32] = f2bf(acc[i][2][r]); orow[48] = f2bf(acc[i][3][r]);
            }
        }
    }
}

// ---------------------------------------------------------------------------
// xbar body: partial column-mean of x (raw fp32), atomic accumulate.
// ---------------------------------------------------------------------------
__device__ __forceinline__ void xbar_body(int id, const float* __restrict__ x,
                                          float* __restrict__ xbar) {
    const int b = id >> 5, chunk = id & 31;
    const int tid = threadIdx.x;
    const float* xp = x + (size_t)b * SF + (size_t)chunk * 64 * FDIM;
    float s0 = 0.f, s1 = 0.f;
    for (int r = 0; r < 64; ++r) {
        s0 += xp[(size_t)r * FDIM + tid];
        s1 += xp[(size_t)r * FDIM + tid + 256];
    }
    atomicAdd(&xbar[b * FDIM + tid],       s0 * (1.f / 2048.f));
    atomicAdd(&xbar[b * FDIM + tid + 256], s1 * (1.f / 2048.f));
}

// ---------------------------------------------------------------------------
// kNN body (HW-validated r14): exact SET selection via two-level histogram.
// Shared arrays carved from the fused smem buffer (~1.9 KB of it).
// ---------------------------------------------------------------------------
__device__ __forceinline__ void knn_body(char* smem, int blk,
                                         const float* __restrict__ coords,
                                         u16* __restrict__ nn_out) {
    u32* chist = (u32*)smem;                  // 64  u32  @ 0
    u32* fhist = (u32*)(smem + 256);          // 256 u32  @ 256
    u64* bk    = (u64*)(smem + 1280);         // 64  u64  @ 1280
    u64* wpart = (u64*)(smem + 1792);         // 4   u64
    u32* sc    = (u32*)(smem + 1824);         // 8   u32
    const int b   = blk >> 11;
    const int qi  = blk & (SEQ - 1);
    const int t   = threadIdx.x;
    const int wid = t >> 6, lane = t & 63;
    const size_t qb = (size_t)blk * KNN;

    fhist[t & 255] = 0;
    if (t < 64) chist[t] = 0;
    if (t == 0) { sc[2] = 0; sc[3] = 0; }

    const float* cb = coords + (size_t)b * SEQ * 3;
    const float qx = cb[qi * 3 + 0];
    const float qy = cb[qi * 3 + 1];
    const float qz = cb[qi * 3 + 2];

    float dist[8];
    int   ib[8];
    u64 tmin = ~0ull;
#pragma unroll
    for (int i = 0; i < 8; ++i) {
        int c = i * 256 + t;
        float dx = __fsub_rn(cb[c * 3 + 0], qx);
        float dy = __fsub_rn(cb[c * 3 + 1], qy);
        float dz = __fsub_rn(cb[c * 3 + 2], qz);
        // numpy order: (dx*dx + dy*dy) + dz*dz, no FMA, IEEE sqrt
        float d2 = __fadd_rn(__fadd_rn(__fmul_rn(dx, dx), __fmul_rn(dy, dy)),
                             __fmul_rn(dz, dz));
        dist[i] = __fsqrt_rn(d2);
        ib[i] = (int)(dist[i] * 8192.0f);
        u64 key = (((u64)__float_as_uint(dist[i])) << 32) | (u32)c;
        tmin = min_u64(tmin, key);
    }
    tmin = min_u64(tmin, shfl_xor_u64(tmin, 1));
    tmin = min_u64(tmin, shfl_xor_u64(tmin, 2));
    tmin = min_u64(tmin, shfl_xor_u64(tmin, 4));
    tmin = min_u64(tmin, shfl_xor_u64(tmin, 8));
    tmin = min_u64(tmin, shfl_xor_u64(tmin, 16));
    tmin = min_u64(tmin, shfl_xor_u64(tmin, 32));
    if (lane == 0) wpart[wid] = tmin;
    __syncthreads();                                  // B1

#pragma unroll
    for (int i = 0; i < 8; ++i) atomicAdd(&chist[ib[i] >> 8], 1u);
    const u64 M = min_u64(min_u64(wpart[0], wpart[1]),
                          min_u64(wpart[2], wpart[3]));
    __syncthreads();                                  // B2

    if (t < 64) {
        u32 h = chist[t];
        u32 cum = h;
#pragma unroll
        for (int d = 1; d < 64; d <<= 1) {
            u32 v = (u32)__shfl_up((int)cum, d, 64);
            if (t >= d) cum += v;
        }
        u64 bal = __ballot(cum >= 33);
        int Bc = __ffsll((long long)bal) - 1;
        u32 excl = cum - h;
        u32 base = (u32)__shfl((int)excl, Bc, 64);
        if (t == 0) { sc[0] = (u32)Bc; sc[1] = base; }
    }
    __syncthreads();                                  // B3

    {
        const int Bc = (int)sc[0];
#pragma unroll
        for (int i = 0; i < 8; ++i)
            if ((ib[i] >> 8) == Bc) atomicAdd(&fhist[ib[i] & 255], 1u);
    }
    __syncthreads();                                  // B4

    if (t < 64) {
        const u32 Bc = sc[0], base = sc[1];
        u32 f0 = fhist[t * 4 + 0], f1 = fhist[t * 4 + 1];
        u32 f2 = fhist[t * 4 + 2], f3 = fhist[t * 4 + 3];
        u32 s = f0 + f1 + f2 + f3;
        u32 cum = s;
#pragma unroll
        for (int d = 1; d < 64; d <<= 1) {
            u32 v = (u32)__shfl_up((int)cum, d, 64);
            if (t >= d) cum += v;
        }
        u32 E = base + (cum - s);
        u32 c0 = E + f0, c1 = c0 + f1, c2 = c1 + f2, c3 = c2 + f3;
        u64 bal = __ballot(c3 >= 33);
        int L = __ffsll((long long)bal) - 1;
        if (t == L) {
            int j = (c0 >= 33) ? 0 : (c1 >= 33) ? 1 : (c2 >= 33) ? 2 : 3;
            sc[4] = (Bc << 8) | (u32)(t * 4 + j);     // IBT
        }
    }
    __syncthreads();                                  // B5

    {
        const int ibt = (int)sc[4];
#pragma unroll
        for (int i = 0; i < 8; ++i) {
            int c = i * 256 + t;
            u64 key = (((u64)__float_as_uint(dist[i])) << 32) | (u32)c;
            if (ib[i] < ibt) {
                if (key != M) {
                    u32 pos = atomicAdd(&sc[2], 1u);
                    nn_out[qb + pos] = (u16)c;
                }
            } else if (ib[i] == ibt) {
                u32 bp = atomicAdd(&sc[3], 1u);
                if (bp < 64) bk[bp] = key;
            }
        }
    }
    __syncthreads();                                  // B6

    if (t < 64) {
        const u32 m = sc[2];
        const int n = (int)min(sc[3], 64u);
        const int need = 32 - (int)m;
        u64 k = (t < n) ? bk[t] : ~0ull;
        if (k == M) k = ~0ull;
#pragma unroll 1
        for (int r = 0; r < need; ++r) {
            u64 g = k;
            g = min_u64(g, shfl_xor_u64(g, 1));
            g = min_u64(g, shfl_xor_u64(g, 2));
            g = min_u64(g, shfl_xor_u64(g, 4));
            g = min_u64(g, shfl_xor_u64(g, 8));
            g = min_u64(g, shfl_xor_u64(g, 16));
            g = min_u64(g, shfl_xor_u64(g, 32));
            if (k == g) {
                nn_out[qb + m + r] = (u16)(g & 0x7FF);
                k = ~0ull;
            }
        }
    }
}

// ---------------------------------------------------------------------------
// FUSED launch (r16): gemm (768 blocks) + xbar (128) + knn (8192) in ONE
// dispatch — single-stream overlap of the independent pipeline branches
// (knn/xbar don't depend on cast/gemm; MFMA and VALU pipes co-schedule,
// m114). Block-uniform branch; knn LDS carved from gemm's 16 KB buffer.
// ---------------------------------------------------------------------------
__global__ __launch_bounds__(256) void fused_gk(const bf16_t* __restrict__ xb,
                                                const bf16_t* __restrict__ wqb,
                                                const bf16_t* __restrict__ wkb,
                                                const bf16_t* __restrict__ wvb,
                                                float* __restrict__ qout,
                                                bf16_t* __restrict__ kvout,
                                                const float* __restrict__ coords,
                                                u16* __restrict__ nn_out,
                                                const float* __restrict__ x,
                                                float* __restrict__ xbar) {
    __shared__ __align__(16) char smem[128 * 32 * 2 * sizeof(bf16_t)];   // 16 KB
    const int bid = blockIdx.x;
    if (bid < GEMM_NB) {
        gemm_body(smem, bid, xb, wqb, wkb, wvb, qout, kvout);
    } else if (bid < GEMM_NB + XBAR_NB) {
        xbar_body(bid - GEMM_NB, x, xbar);
    } else {
        knn_body(smem, bid - GEMM_NB - XBAR_NB, coords, nn_out);
    }
}

// ---------------------------------------------------------------------------
// Attention v4 (r15, HW-validated): barrier-free, one wave per (q,h),
// single up-front gather epoch, XCD swizzle.
// ---------------------------------------------------------------------------
__global__ __launch_bounds__(256, 8) void attn_kernel(const bf16_t* __restrict__ kv,
                                                      const u16* __restrict__ nn,
                                                      float* __restrict__ out) {
    __shared__ float qsl[4][64];                          // 1 KB, per-wave slot
    const int i   = blockIdx.x;                           // 0..16383
    const int b   = (i & 7) >> 1;                         // XCD pair -> batch
    const int jb  = ((i >> 3) << 1) | (i & 1);            // 0..4095, bijective
    const int tid = threadIdx.x;
    const int wid = tid >> 6, lane = tid & 63;
    const int gid = (jb << 2) | wid;                      // 0..16383 per batch
    const int qi  = gid >> 3, h = gid & 7;
    const int blk = (b << 11) | qi;

    int sreg = 0;
    if (lane < KNN) sreg = (int)nn[(size_t)blk * KNN + lane] & (SEQ - 1);
    qsl[wid][lane] = out[(size_t)blk * FDIM + h * HDIM + lane];   // own q slice
    __asm__ volatile("s_waitcnt lgkmcnt(0)" ::: "memory");
    __builtin_amdgcn_wave_barrier();

    const int j = lane & 31, half = lane >> 5;
    const int rowj = __shfl(sreg, j, 64);
    const bf16_t* kreg = kv + ((size_t)((b << 11) + rowj)) * FDIM + h * HDIM + half * 32;
    uint4 k0 = *(const uint4*)(kreg + 0);
    uint4 k1 = *(const uint4*)(kreg + 8);
    uint4 k2 = *(const uint4*)(kreg + 16);
    uint4 k3 = *(const uint4*)(kreg + 24);

    const int g = lane >> 4, l = lane & 15;
    const bf16_t* vbase = kv + BSF + ((size_t)(b << 11)) * FDIM + h * HDIM + l * 4;
    uint2 vv[8];
#pragma unroll
    for (int t2 = 0; t2 < 8; ++t2) {
        const int row = __shfl(sreg, (g << 3) | t2, 64);
        vv[t2] = *(const uint2*)(vbase + (size_t)row * FDIM);   // 4 bf16
    }

    const float* qp = &qsl[wid][half * 32];
    float acc = 0.f;
    {
        float f0, f1, f2, f3, f4, f5, f6, f7;
        bf2x2(k0.x, f0, f1); bf2x2(k0.y, f2, f3);
        bf2x2(k0.z, f4, f5); bf2x2(k0.w, f6, f7);
        acc += qp[0] * f0 + qp[1] * f1 + qp[2] * f2 + qp[3] * f3
             + qp[4] * f4 + qp[5] * f5 + qp[6] * f6 + qp[7] * f7;
        bf2x2(k1.x, f0, f1); bf2x2(k1.y, f2, f3);
        bf2x2(k1.z, f4, f5); bf2x2(k1.w, f6, f7);
        acc += qp[8] * f0 + qp[9] * f1 + qp[10] * f2 + qp[11] * f3
             + qp[12] * f4 + qp[13] * f5 + qp[14] * f6 + qp[15] * f7;
        bf2x2(k2.x, f0, f1); bf2x2(k2.y, f2, f3);
        bf2x2(k2.z, f4, f5); bf2x2(k2.w, f6, f7);
        acc += qp[16] * f0 + qp[17] * f1 + qp[18] * f2 + qp[19] * f3
             + qp[20] * f4 + qp[21] * f5 + qp[22] * f6 + qp[23] * f7;
        bf2x2(k3.x, f0, f1); bf2x2(k3.y, f2, f3);
        bf2x2(k3.z, f4, f5); bf2x2(k3.w, f6, f7);
        acc += qp[24] * f0 + qp[25] * f1 + qp[26] * f2 + qp[27] * f3
             + qp[28] * f4 + qp[29] * f5 + qp[30] * f6 + qp[31] * f7;
    }
    acc += __shfl_xor(acc, 32, 64);
    float s = acc * 0.125f;                 // 1/sqrt(64)
    float m = s;
    m = fmaxf(m, __shfl_xor(m, 1, 64));
    m = fmaxf(m, __shfl_xor(m, 2, 64));
    m = fmaxf(m, __shfl_xor(m, 4, 64));
    m = fmaxf(m, __shfl_xor(m, 8, 64));
    m = fmaxf(m, __shfl_xor(m, 16, 64));
    float e = __expf(s - m);
    float sum = e;
    sum += __shfl_xor(sum, 1, 64);
    sum += __shfl_xor(sum, 2, 64);
    sum += __shfl_xor(sum, 4, 64);
    sum += __shfl_xor(sum, 8, 64);
    sum += __shfl_xor(sum, 16, 64);
    float w = e / sum;                      // valid per j on lanes j and j+32

    float o0 = 0.f, o1 = 0.f, o2 = 0.f, o3 = 0.f;
#pragma unroll
    for (int t2 = 0; t2 < 8; ++t2) {
        const float wj = __shfl(w, (g << 3) | t2, 64);
        float f0, f1, f2, f3;
        bf2x2(vv[t2].x, f0, f1); bf2x2(vv[t2].y, f2, f3);
        o0 += wj * f0; o1 += wj * f1; o2 += wj * f2; o3 += wj * f3;
    }
    o0 += __shfl_xor(o0, 16, 64); o0 += __shfl_xor(o0, 32, 64);
    o1 += __shfl_xor(o1, 16, 64); o1 += __shfl_xor(o1, 32, 64);
    o2 += __shfl_xor(o2, 16, 64); o2 += __shfl_xor(o2, 32, 64);
    o3 += __shfl_xor(o3, 16, 64); o3 += __shfl_xor(o3, 32, 64);
    if (g == 0) {
        float4 ov = make_float4(o0, o1, o2, o3);
        *(float4*)(out + (size_t)blk * FDIM + h * HDIM + l * 4) = ov;
    }
}

// ---------------------------------------------------------------------------
// metric = xbar @ Wk^T  (xbar produced in fused_gk), fp32
// ---------------------------------------------------------------------------
__global__ __launch_bounds__(256) void metric_kernel(const float* __restrict__ xbar,
                                                     const float* __restrict__ Wk,
                                                     float* __restrict__ metric) {
    const int o = blockIdx.x * 256 + threadIdx.x;   // 2048 outputs
    const int b = o >> 9, f = o & 511;
    const float* xb = xbar + b * FDIM;
    const float* wr = Wk + (size_t)f * FDIM;
    float acc = 0.f;
#pragma unroll 4
    for (int kk = 0; kk < FDIM; kk += 4) {
        float4 wv = *(const float4*)(wr + kk);
        acc += xb[kk + 0] * wv.x + xb[kk + 1] * wv.y
             + xb[kk + 2] * wv.z + xb[kk + 3] * wv.w;
    }
    metric[o] = acc;
}

// ---------------------------------------------------------------------------
extern "C" void kernel_launch(void* const* d_in, const int* in_sizes, int n_in,
                              void* d_out, int out_size, void* d_ws, size_t ws_size,
                              hipStream_t stream) {
    const float* x      = (const float*)d_in[0];
    const float* coords = (const float*)d_in[1];
    const float* Wq     = (const float*)d_in[2];
    const float* Wk     = (const float*)d_in[3];
    const float* Wv     = (const float*)d_in[4];
    float* out    = (float*)d_out;
    float* metric = out + BSF;

    // ws layout (26.0 MiB):
    //   xb bf16 BSF (8 MiB) | wqb/wkb/wvb bf16 (1.5 MiB) | kv bf16 2*BSF (16 MiB)
    //   | nn u16 (0.5 MiB) | xbar f32 (8 KiB)
    char* p = (char*)d_ws;
    bf16_t* xb   = (bf16_t*)p;                       p += BSF * sizeof(bf16_t);
    bf16_t* wqb  = (bf16_t*)p;                       p += (size_t)FDIM * FDIM * sizeof(bf16_t);
    bf16_t* wkb  = (bf16_t*)p;                       p += (size_t)FDIM * FDIM * sizeof(bf16_t);
    bf16_t* wvb  = (bf16_t*)p;                       p += (size_t)FDIM * FDIM * sizeof(bf16_t);
    bf16_t* kv   = (bf16_t*)p;                       p += 2 * BSF * sizeof(bf16_t);
    u16*    nn   = (u16*)p;                          p += (size_t)BATCH * SEQ * KNN * sizeof(u16);
    float*  xbar = (float*)p;

    cast_kernel<<<dim3(BSF / 8 / 256, 1, 4), 256, 0, stream>>>(x, Wq, Wk, Wv,
                                                               xb, wqb, wkb, wvb);
    hipMemsetAsync(xbar, 0, BATCH * FDIM * sizeof(float), stream);

    // fused: gemm (q->d_out fp32, k/v->ws bf16) + xbar + knn, one dispatch
    fused_gk<<<GEMM_NB + XBAR_NB + BATCH * SEQ, 256, 0, stream>>>(
        xb, wqb, wkb, wvb, out, kv, coords, nn, x, xbar);

    metric_kernel<<<(BATCH * NHEAD * HDIM) / 256, 256, 0, stream>>>(xbar, Wk, metric);

    attn_kernel<<<(BATCH * SEQ * NHEAD) / 4, 256, 0, stream>>>(kv, nn, out);
}

// Round 17
// 188.741 us; speedup vs baseline: 1.1401x; 1.1401x over previous
//
#include <hip/hip_runtime.h>
#include <stdint.h>

#define BATCH 4
#define SEQ   2048
#define FDIM  512
#define NHEAD 8
#define HDIM  64
#define KNN   32

typedef unsigned int u32;
typedef unsigned long long u64;
typedef unsigned short u16;
typedef unsigned short bf16_t;

typedef __attribute__((ext_vector_type(8))) short short8;   // 8 bf16 = 4 VGPRs
typedef __attribute__((ext_vector_type(4))) float f32x4;

#define SF  ((size_t)SEQ * FDIM)            // 1,048,576 per-batch elements
#define BSF ((size_t)BATCH * SF)            // 4,194,304

// fused_ck grid layout
#define CAST_NB 2432                        // 2048 (x) + 3*128 (weights)
#define XBAR_NB 128
#define ATTN_NB (BATCH * SEQ * NHEAD / 4)   // 16384

__device__ __forceinline__ bf16_t f2bf(float f) {
    u32 x = __float_as_uint(f);
    return (bf16_t)((x + 0x7FFFu + ((x >> 16) & 1u)) >> 16);   // RNE
}
__device__ __forceinline__ float bf2f(bf16_t u) { return __uint_as_float(((u32)u) << 16); }
__device__ __forceinline__ void bf2x2(u32 p, float& a, float& b) {
    a = __uint_as_float(p << 16);          // element 2i (low u16)
    b = __uint_as_float(p & 0xFFFF0000u);  // element 2i+1 (high u16)
}
__device__ __forceinline__ u64 min_u64(u64 a, u64 b) { return a < b ? a : b; }
__device__ __forceinline__ u64 shfl_xor_u64(u64 v, int m) {
    int lo = __shfl_xor((int)(u32)v, m, 64);
    int hi = __shfl_xor((int)(u32)(v >> 32), m, 64);
    return (((u64)(u32)hi) << 32) | (u32)lo;
}

// ---------------------------------------------------------------------------
// cast body: fp32 -> bf16, 8 elem/thread. Linear block id selects tensor.
// ---------------------------------------------------------------------------
__device__ __forceinline__ void cast_body(int cid,
                                          const float* __restrict__ x,
                                          const float* __restrict__ wq,
                                          const float* __restrict__ wk,
                                          const float* __restrict__ wv,
                                          bf16_t* __restrict__ xb,
                                          bf16_t* __restrict__ wqb,
                                          bf16_t* __restrict__ wkb,
                                          bf16_t* __restrict__ wvb) {
    int z, blk;
    if (cid < 2048) { z = 0; blk = cid; }
    else { int d = cid - 2048; z = 1 + (d >> 7); blk = d & 127; }
    const float* src = (z == 0) ? x : (z == 1) ? wq : (z == 2) ? wk : wv;
    bf16_t* dst      = (z == 0) ? xb : (z == 1) ? wqb : (z == 2) ? wkb : wvb;
    size_t idx = (size_t)blk * 256 + threadIdx.x;
    const float4 a = ((const float4*)src)[idx * 2 + 0];
    const float4 b = ((const float4*)src)[idx * 2 + 1];
    uint4 o;
    o.x = (u32)f2bf(a.x) | ((u32)f2bf(a.y) << 16);
    o.y = (u32)f2bf(a.z) | ((u32)f2bf(a.w) << 16);
    o.z = (u32)f2bf(b.x) | ((u32)f2bf(b.y) << 16);
    o.w = (u32)f2bf(b.z) | ((u32)f2bf(b.w) << 16);
    ((uint4*)dst)[idx] = o;
}

// ---------------------------------------------------------------------------
// xbar body: partial column-mean of x (raw fp32), atomic accumulate.
// ---------------------------------------------------------------------------
__device__ __forceinline__ void xbar_body(int id, const float* __restrict__ x,
                                          float* __restrict__ xbar) {
    const int b = id >> 5, chunk = id & 31;
    const int tid = threadIdx.x;
    const float* xp = x + (size_t)b * SF + (size_t)chunk * 64 * FDIM;
    float s0 = 0.f, s1 = 0.f;
    for (int r = 0; r < 64; ++r) {
        s0 += xp[(size_t)r * FDIM + tid];
        s1 += xp[(size_t)r * FDIM + tid + 256];
    }
    atomicAdd(&xbar[b * FDIM + tid],       s0 * (1.f / 2048.f));
    atomicAdd(&xbar[b * FDIM + tid + 256], s1 * (1.f / 2048.f));
}

// ---------------------------------------------------------------------------
// kNN body (HW-validated r14): exact SET selection via two-level histogram.
// Order-free output (nn used only as boolean mask); set = {33 smallest
// (dist,idx) keys} \ {min key} == stable argsort[1:33].
// ---------------------------------------------------------------------------
__device__ __forceinline__ void knn_body(char* smem, int blk,
                                         const float* __restrict__ coords,
                                         u16* __restrict__ nn_out) {
    u32* chist = (u32*)smem;                  // 64  u32
    u32* fhist = (u32*)(smem + 256);          // 256 u32
    u64* bk    = (u64*)(smem + 1280);         // 64  u64
    u64* wpart = (u64*)(smem + 1792);         // 4   u64
    u32* sc    = (u32*)(smem + 1824);         // 8   u32
    const int b   = blk >> 11;
    const int qi  = blk & (SEQ - 1);
    const int t   = threadIdx.x;
    const int wid = t >> 6, lane = t & 63;
    const size_t qb = (size_t)blk * KNN;

    fhist[t & 255] = 0;
    if (t < 64) chist[t] = 0;
    if (t == 0) { sc[2] = 0; sc[3] = 0; }

    const float* cb = coords + (size_t)b * SEQ * 3;
    const float qx = cb[qi * 3 + 0];
    const float qy = cb[qi * 3 + 1];
    const float qz = cb[qi * 3 + 2];

    float dist[8];
    int   ib[8];
    u64 tmin = ~0ull;
#pragma unroll
    for (int i = 0; i < 8; ++i) {
        int c = i * 256 + t;
        float dx = __fsub_rn(cb[c * 3 + 0], qx);
        float dy = __fsub_rn(cb[c * 3 + 1], qy);
        float dz = __fsub_rn(cb[c * 3 + 2], qz);
        // numpy order: (dx*dx + dy*dy) + dz*dz, no FMA, IEEE sqrt
        float d2 = __fadd_rn(__fadd_rn(__fmul_rn(dx, dx), __fmul_rn(dy, dy)),
                             __fmul_rn(dz, dz));
        dist[i] = __fsqrt_rn(d2);
        ib[i] = (int)(dist[i] * 8192.0f);
        u64 key = (((u64)__float_as_uint(dist[i])) << 32) | (u32)c;
        tmin = min_u64(tmin, key);
    }
    tmin = min_u64(tmin, shfl_xor_u64(tmin, 1));
    tmin = min_u64(tmin, shfl_xor_u64(tmin, 2));
    tmin = min_u64(tmin, shfl_xor_u64(tmin, 4));
    tmin = min_u64(tmin, shfl_xor_u64(tmin, 8));
    tmin = min_u64(tmin, shfl_xor_u64(tmin, 16));
    tmin = min_u64(tmin, shfl_xor_u64(tmin, 32));
    if (lane == 0) wpart[wid] = tmin;
    __syncthreads();                                  // B1

#pragma unroll
    for (int i = 0; i < 8; ++i) atomicAdd(&chist[ib[i] >> 8], 1u);
    const u64 M = min_u64(min_u64(wpart[0], wpart[1]),
                          min_u64(wpart[2], wpart[3]));
    __syncthreads();                                  // B2

    if (t < 64) {
        u32 h = chist[t];
        u32 cum = h;
#pragma unroll
        for (int d = 1; d < 64; d <<= 1) {
            u32 v = (u32)__shfl_up((int)cum, d, 64);
            if (t >= d) cum += v;
        }
        u64 bal = __ballot(cum >= 33);
        int Bc = __ffsll((long long)bal) - 1;
        u32 excl = cum - h;
        u32 base = (u32)__shfl((int)excl, Bc, 64);
        if (t == 0) { sc[0] = (u32)Bc; sc[1] = base; }
    }
    __syncthreads();                                  // B3

    {
        const int Bc = (int)sc[0];
#pragma unroll
        for (int i = 0; i < 8; ++i)
            if ((ib[i] >> 8) == Bc) atomicAdd(&fhist[ib[i] & 255], 1u);
    }
    __syncthreads();                                  // B4

    if (t < 64) {
        const u32 Bc = sc[0], base = sc[1];
        u32 f0 = fhist[t * 4 + 0], f1 = fhist[t * 4 + 1];
        u32 f2 = fhist[t * 4 + 2], f3 = fhist[t * 4 + 3];
        u32 s = f0 + f1 + f2 + f3;
        u32 cum = s;
#pragma unroll
        for (int d = 1; d < 64; d <<= 1) {
            u32 v = (u32)__shfl_up((int)cum, d, 64);
            if (t >= d) cum += v;
        }
        u32 E = base + (cum - s);
        u32 c0 = E + f0, c1 = c0 + f1, c2 = c1 + f2, c3 = c2 + f3;
        u64 bal = __ballot(c3 >= 33);
        int L = __ffsll((long long)bal) - 1;
        if (t == L) {
            int j = (c0 >= 33) ? 0 : (c1 >= 33) ? 1 : (c2 >= 33) ? 2 : 3;
            sc[4] = (Bc << 8) | (u32)(t * 4 + j);     // IBT
        }
    }
    __syncthreads();                                  // B5

    {
        const int ibt = (int)sc[4];
#pragma unroll
        for (int i = 0; i < 8; ++i) {
            int c = i * 256 + t;
            u64 key = (((u64)__float_as_uint(dist[i])) << 32) | (u32)c;
            if (ib[i] < ibt) {
                if (key != M) {
                    u32 pos = atomicAdd(&sc[2], 1u);
                    nn_out[qb + pos] = (u16)c;
                }
            } else if (ib[i] == ibt) {
                u32 bp = atomicAdd(&sc[3], 1u);
                if (bp < 64) bk[bp] = key;
            }
        }
    }
    __syncthreads();                                  // B6

    if (t < 64) {
        const u32 m = sc[2];
        const int n = (int)min(sc[3], 64u);
        const int need = 32 - (int)m;
        u64 k = (t < n) ? bk[t] : ~0ull;
        if (k == M) k = ~0ull;
#pragma unroll 1
        for (int r = 0; r < need; ++r) {
            u64 g = k;
            g = min_u64(g, shfl_xor_u64(g, 1));
            g = min_u64(g, shfl_xor_u64(g, 2));
            g = min_u64(g, shfl_xor_u64(g, 4));
            g = min_u64(g, shfl_xor_u64(g, 8));
            g = min_u64(g, shfl_xor_u64(g, 16));
            g = min_u64(g, shfl_xor_u64(g, 32));
            if (k == g) {
                nn_out[qb + m + r] = (u16)(g & 0x7FF);
                k = ~0ull;
            }
        }
    }
}

// ---------------------------------------------------------------------------
// FUSED dispatch 1: cast + xbar + knn — memory-bound bodies (cast/xbar)
// co-scheduled with VALU-bound knn; NO gemm (r16 lesson: staging-heavy gemm
// shares badly). Saves 2 launch gaps.
// ---------------------------------------------------------------------------
__global__ __launch_bounds__(256) void fused_ck(const float* __restrict__ x,
                                                const float* __restrict__ wq,
                                                const float* __restrict__ wk,
                                                const float* __restrict__ wv,
                                                bf16_t* __restrict__ xb,
                                                bf16_t* __restrict__ wqb,
                                                bf16_t* __restrict__ wkb,
                                                bf16_t* __restrict__ wvb,
                                                const float* __restrict__ coords,
                                                u16* __restrict__ nn_out,
                                                float* __restrict__ xbar) {
    __shared__ __align__(16) char smem[1856];   // knn scratch only
    const int bid = blockIdx.x;
    if (bid < CAST_NB) {
        cast_body(bid, x, wq, wk, wv, xb, wqb, wkb, wvb);
    } else if (bid < CAST_NB + XBAR_NB) {
        xbar_body(bid - CAST_NB, x, xbar);
    } else {
        knn_body(smem, bid - CAST_NB - XBAR_NB, coords, nn_out);
    }
}

// ---------------------------------------------------------------------------
// GEMM (standalone again — r15 HW-validated body): 128x128 tile, BK=32.
// z=0 -> q (fp32 to d_out); z=1,2 -> k,v (bf16 to ws).
// ---------------------------------------------------------------------------
__global__ __launch_bounds__(256) void gemm_mfma(const bf16_t* __restrict__ xb,
                                                 const bf16_t* __restrict__ wqb,
                                                 const bf16_t* __restrict__ wkb,
                                                 const bf16_t* __restrict__ wvb,
                                                 float* __restrict__ qout,
                                                 bf16_t* __restrict__ kvout) {
    __shared__ __align__(16) bf16_t As[128 * 32];
    __shared__ __align__(16) bf16_t Bs[128 * 32];
    const int z = blockIdx.z;
    const bf16_t* W = (z == 0) ? wqb : (z == 1) ? wkb : wvb;
    const int tid  = threadIdx.x;
    const int wid  = tid >> 6, lane = tid & 63;
    const int m16  = lane & 15, quad = lane >> 4;
    const int wm   = (wid & 1) * 64;
    const int wn   = (wid >> 1) * 64;
    const int m0   = blockIdx.y * 128;
    const int n0   = blockIdx.x * 128;

    const int sr = tid >> 2, sc = (tid & 3) * 8;
    const bf16_t* agp = xb + (size_t)(m0 + sr) * FDIM + sc;
    const bf16_t* bgp = W  + (size_t)(n0 + sr) * FDIM + sc;

    f32x4 acc[4][4];
#pragma unroll
    for (int i = 0; i < 4; ++i)
#pragma unroll
        for (int j = 0; j < 4; ++j) acc[i][j] = (f32x4){0.f, 0.f, 0.f, 0.f};

#pragma unroll 1
    for (int k0 = 0; k0 < FDIM; k0 += 32) {
        uint4 a0 = *(const uint4*)(agp + k0);
        uint4 a1 = *(const uint4*)(agp + (size_t)64 * FDIM + k0);
        uint4 b0 = *(const uint4*)(bgp + k0);
        uint4 b1 = *(const uint4*)(bgp + (size_t)64 * FDIM + k0);
        __syncthreads();
        *(uint4*)(As + sr * 32 + sc)        = a0;
        *(uint4*)(As + (sr + 64) * 32 + sc) = a1;
        *(uint4*)(Bs + sr * 32 + sc)        = b0;
        *(uint4*)(Bs + (sr + 64) * 32 + sc) = b1;
        __syncthreads();

        short8 af[4], bfr[4];
#pragma unroll
        for (int i = 0; i < 4; ++i)
            af[i] = *(const short8*)(As + (wm + i * 16 + m16) * 32 + quad * 8);
#pragma unroll
        for (int j = 0; j < 4; ++j)
            bfr[j] = *(const short8*)(Bs + (wn + j * 16 + m16) * 32 + quad * 8);
#pragma unroll
        for (int i = 0; i < 4; ++i)
#pragma unroll
            for (int j = 0; j < 4; ++j)
                acc[i][j] = __builtin_amdgcn_mfma_f32_16x16x32_bf16(af[i], bfr[j],
                                                                    acc[i][j], 0, 0, 0);
    }

    if (z == 0) {
#pragma unroll
        for (int i = 0; i < 4; ++i) {
            const int rowb = m0 + wm + i * 16 + quad * 4;
#pragma unroll
            for (int r = 0; r < 4; ++r) {
                float* orow = qout + (size_t)(rowb + r) * FDIM + n0 + wn + m16;
                orow[ 0] = acc[i][0][r]; orow[16] = acc[i][1][r];
                orow[32] = acc[i][2][r]; orow[48] = acc[i][3][r];
            }
        }
    } else {
        bf16_t* base = kvout + (size_t)(z - 1) * BSF;
#pragma unroll
        for (int i = 0; i < 4; ++i) {
            const int rowb = m0 + wm + i * 16 + quad * 4;
#pragma unroll
            for (int r = 0; r < 4; ++r) {
                bf16_t* orow = base + (size_t)(rowb + r) * FDIM + n0 + wn + m16;
                orow[ 0] = f2bf(acc[i][0][r]); orow[16] = f2bf(acc[i][1][r]);
                orow[32] = f2bf(acc[i][2][r]); orow[48] = f2bf(acc[i][3][r]);
            }
        }
    }
}

// ---------------------------------------------------------------------------
// metric body: metric = xbar @ Wk^T (fp32), 8 blocks of 256.
// ---------------------------------------------------------------------------
__device__ __forceinline__ void metric_body(int mb, const float* __restrict__ xbar,
                                            const float* __restrict__ Wk,
                                            float* __restrict__ metric) {
    const int o = mb * 256 + threadIdx.x;           // 2048 outputs
    const int b = o >> 9, f = o & 511;
    const float* xb = xbar + b * FDIM;
    const float* wr = Wk + (size_t)f * FDIM;
    float acc = 0.f;
#pragma unroll 4
    for (int kk = 0; kk < FDIM; kk += 4) {
        float4 wv = *(const float4*)(wr + kk);
        acc += xb[kk + 0] * wv.x + xb[kk + 1] * wv.y
             + xb[kk + 2] * wv.z + xb[kk + 3] * wv.w;
    }
    metric[o] = acc;
}

// ---------------------------------------------------------------------------
// FUSED dispatch 2: attention v4 (r15 HW-validated: barrier-free, one wave
// per (q,h), single gather epoch, XCD swizzle) + metric tail (8 blocks).
// ---------------------------------------------------------------------------
__global__ __launch_bounds__(256, 8) void fused_am(const bf16_t* __restrict__ kv,
                                                   const u16* __restrict__ nn,
                                                   float* __restrict__ out,
                                                   const float* __restrict__ xbar,
                                                   const float* __restrict__ Wk,
                                                   float* __restrict__ metric) {
    __shared__ float qsl[4][64];                          // 1 KB, per-wave slot
    const int i   = blockIdx.x;
    if (i >= ATTN_NB) { metric_body(i - ATTN_NB, xbar, Wk, metric); return; }
    const int b   = (i & 7) >> 1;                         // XCD pair -> batch
    const int jb  = ((i >> 3) << 1) | (i & 1);            // 0..4095, bijective
    const int tid = threadIdx.x;
    const int wid = tid >> 6, lane = tid & 63;
    const int gid = (jb << 2) | wid;                      // 0..16383 per batch
    const int qi  = gid >> 3, h = gid & 7;
    const int blk = (b << 11) | qi;

    int sreg = 0;
    if (lane < KNN) sreg = (int)nn[(size_t)blk * KNN + lane] & (SEQ - 1);
    qsl[wid][lane] = out[(size_t)blk * FDIM + h * HDIM + lane];   // own q slice
    __asm__ volatile("s_waitcnt lgkmcnt(0)" ::: "memory");
    __builtin_amdgcn_wave_barrier();

    const int j = lane & 31, half = lane >> 5;
    const int rowj = __shfl(sreg, j, 64);
    const bf16_t* kreg = kv + ((size_t)((b << 11) + rowj)) * FDIM + h * HDIM + half * 32;
    uint4 k0 = *(const uint4*)(kreg + 0);
    uint4 k1 = *(const uint4*)(kreg + 8);
    uint4 k2 = *(const uint4*)(kreg + 16);
    uint4 k3 = *(const uint4*)(kreg + 24);

    const int g = lane >> 4, l = lane & 15;
    const bf16_t* vbase = kv + BSF + ((size_t)(b << 11)) * FDIM + h * HDIM + l * 4;
    uint2 vv[8];
#pragma unroll
    for (int t2 = 0; t2 < 8; ++t2) {
        const int row = __shfl(sreg, (g << 3) | t2, 64);
        vv[t2] = *(const uint2*)(vbase + (size_t)row * FDIM);   // 4 bf16
    }

    const float* qp = &qsl[wid][half * 32];
    float acc = 0.f;
    {
        float f0, f1, f2, f3, f4, f5, f6, f7;
        bf2x2(k0.x, f0, f1); bf2x2(k0.y, f2, f3);
        bf2x2(k0.z, f4, f5); bf2x2(k0.w, f6, f7);
        acc += qp[0] * f0 + qp[1] * f1 + qp[2] * f2 + qp[3] * f3
             + qp[4] * f4 + qp[5] * f5 + qp[6] * f6 + qp[7] * f7;
        bf2x2(k1.x, f0, f1); bf2x2(k1.y, f2, f3);
        bf2x2(k1.z, f4, f5); bf2x2(k1.w, f6, f7);
        acc += qp[8] * f0 + qp[9] * f1 + qp[10] * f2 + qp[11] * f3
             + qp[12] * f4 + qp[13] * f5 + qp[14] * f6 + qp[15] * f7;
        bf2x2(k2.x, f0, f1); bf2x2(k2.y, f2, f3);
        bf2x2(k2.z, f4, f5); bf2x2(k2.w, f6, f7);
        acc += qp[16] * f0 + qp[17] * f1 + qp[18] * f2 + qp[19] * f3
             + qp[20] * f4 + qp[21] * f5 + qp[22] * f6 + qp[23] * f7;
        bf2x2(k3.x, f0, f1); bf2x2(k3.y, f2, f3);
        bf2x2(k3.z, f4, f5); bf2x2(k3.w, f6, f7);
        acc += qp[24] * f0 + qp[25] * f1 + qp[26] * f2 + qp[27] * f3
             + qp[28] * f4 + qp[29] * f5 + qp[30] * f6 + qp[31] * f7;
    }
    acc += __shfl_xor(acc, 32, 64);
    float s = acc * 0.125f;                 // 1/sqrt(64)
    float m = s;
    m = fmaxf(m, __shfl_xor(m, 1, 64));
    m = fmaxf(m, __shfl_xor(m, 2, 64));
    m = fmaxf(m, __shfl_xor(m, 4, 64));
    m = fmaxf(m, __shfl_xor(m, 8, 64));
    m = fmaxf(m, __shfl_xor(m, 16, 64));
    float e = __expf(s - m);
    float sum = e;
    sum += __shfl_xor(sum, 1, 64);
    sum += __shfl_xor(sum, 2, 64);
    sum += __shfl_xor(sum, 4, 64);
    sum += __shfl_xor(sum, 8, 64);
    sum += __shfl_xor(sum, 16, 64);
    float w = e / sum;                      // valid per j on lanes j and j+32

    float o0 = 0.f, o1 = 0.f, o2 = 0.f, o3 = 0.f;
#pragma unroll
    for (int t2 = 0; t2 < 8; ++t2) {
        const float wj = __shfl(w, (g << 3) | t2, 64);
        float f0, f1, f2, f3;
        bf2x2(vv[t2].x, f0, f1); bf2x2(vv[t2].y, f2, f3);
        o0 += wj * f0; o1 += wj * f1; o2 += wj * f2; o3 += wj * f3;
    }
    o0 += __shfl_xor(o0, 16, 64); o0 += __shfl_xor(o0, 32, 64);
    o1 += __shfl_xor(o1, 16, 64); o1 += __shfl_xor(o1, 32, 64);
    o2 += __shfl_xor(o2, 16, 64); o2 += __shfl_xor(o2, 32, 64);
    o3 += __shfl_xor(o3, 16, 64); o3 += __shfl_xor(o3, 32, 64);
    if (g == 0) {
        float4 ov = make_float4(o0, o1, o2, o3);
        *(float4*)(out + (size_t)blk * FDIM + h * HDIM + l * 4) = ov;
    }
}

// ---------------------------------------------------------------------------
extern "C" void kernel_launch(void* const* d_in, const int* in_sizes, int n_in,
                              void* d_out, int out_size, void* d_ws, size_t ws_size,
                              hipStream_t stream) {
    const float* x      = (const float*)d_in[0];
    const float* coords = (const float*)d_in[1];
    const float* Wq     = (const float*)d_in[2];
    const float* Wk     = (const float*)d_in[3];
    const float* Wv     = (const float*)d_in[4];
    float* out    = (float*)d_out;
    float* metric = out + BSF;

    // ws layout (26.0 MiB):
    //   xb bf16 BSF (8 MiB) | wqb/wkb/wvb bf16 (1.5 MiB) | kv bf16 2*BSF (16 MiB)
    //   | nn u16 (0.5 MiB) | xbar f32 (8 KiB)
    char* p = (char*)d_ws;
    bf16_t* xb   = (bf16_t*)p;                       p += BSF * sizeof(bf16_t);
    bf16_t* wqb  = (bf16_t*)p;                       p += (size_t)FDIM * FDIM * sizeof(bf16_t);
    bf16_t* wkb  = (bf16_t*)p;                       p += (size_t)FDIM * FDIM * sizeof(bf16_t);
    bf16_t* wvb  = (bf16_t*)p;                       p += (size_t)FDIM * FDIM * sizeof(bf16_t);
    bf16_t* kv   = (bf16_t*)p;                       p += 2 * BSF * sizeof(bf16_t);
    u16*    nn   = (u16*)p;                          p += (size_t)BATCH * SEQ * KNN * sizeof(u16);
    float*  xbar = (float*)p;

    hipMemsetAsync(xbar, 0, BATCH * FDIM * sizeof(float), stream);

    // 1) cast + xbar + knn (no gemm — r16 lesson)
    fused_ck<<<CAST_NB + XBAR_NB + BATCH * SEQ, 256, 0, stream>>>(
        x, Wq, Wk, Wv, xb, wqb, wkb, wvb, coords, nn, xbar);

    // 2) gemm standalone: q -> d_out (fp32), k/v -> ws (bf16)
    gemm_mfma<<<dim3(FDIM / 128, (BATCH * SEQ) / 128, 3), 256, 0, stream>>>(
        xb, wqb, wkb, wvb, out, kv);

    // 3) attention + metric tail
    fused_am<<<ATTN_NB + (BATCH * NHEAD * HDIM) / 256, 256, 0, stream>>>(
        kv, nn, out, xbar, Wk, metric);
}

// Round 18
// 184.730 us; speedup vs baseline: 1.1649x; 1.0217x over previous
//
#include <hip/hip_runtime.h>
#include <stdint.h>

#define BATCH 4
#define SEQ   2048
#define FDIM  512
#define NHEAD 8
#define HDIM  64
#define KNN   32

typedef unsigned int u32;
typedef unsigned long long u64;
typedef unsigned short u16;
typedef unsigned short bf16_t;

typedef __attribute__((ext_vector_type(8))) short short8;   // 8 bf16 = 4 VGPRs
typedef __attribute__((ext_vector_type(4))) float f32x4;

#define SF  ((size_t)SEQ * FDIM)            // 1,048,576 per-batch elements
#define BSF ((size_t)BATCH * SF)            // 4,194,304

// fused_ck grid layout
#define CAST_NB 2432                        // 2048 (x) + 3*128 (weights)
#define XPART_NB 128                        // 4 batches x 32 chunks

__device__ __forceinline__ bf16_t f2bf(float f) {
    u32 x = __float_as_uint(f);
    return (bf16_t)((x + 0x7FFFu + ((x >> 16) & 1u)) >> 16);   // RNE
}
__device__ __forceinline__ float bf2f(bf16_t u) { return __uint_as_float(((u32)u) << 16); }
__device__ __forceinline__ void bf2x2(u32 p, float& a, float& b) {
    a = __uint_as_float(p << 16);          // element 2i (low u16)
    b = __uint_as_float(p & 0xFFFF0000u);  // element 2i+1 (high u16)
}
__device__ __forceinline__ u64 min_u64(u64 a, u64 b) { return a < b ? a : b; }
__device__ __forceinline__ u64 shfl_xor_u64(u64 v, int m) {
    int lo = __shfl_xor((int)(u32)v, m, 64);
    int hi = __shfl_xor((int)(u32)(v >> 32), m, 64);
    return (((u64)(u32)hi) << 32) | (u32)lo;
}

// ---------------------------------------------------------------------------
// cast body: fp32 -> bf16, 8 elem/thread. Linear block id selects tensor.
// ---------------------------------------------------------------------------
__device__ __forceinline__ void cast_body(int cid,
                                          const float* __restrict__ x,
                                          const float* __restrict__ wq,
                                          const float* __restrict__ wk,
                                          const float* __restrict__ wv,
                                          bf16_t* __restrict__ xb,
                                          bf16_t* __restrict__ wqb,
                                          bf16_t* __restrict__ wkb,
                                          bf16_t* __restrict__ wvb) {
    int z, blk;
    if (cid < 2048) { z = 0; blk = cid; }
    else { int d = cid - 2048; z = 1 + (d >> 7); blk = d & 127; }
    const float* src = (z == 0) ? x : (z == 1) ? wq : (z == 2) ? wk : wv;
    bf16_t* dst      = (z == 0) ? xb : (z == 1) ? wqb : (z == 2) ? wkb : wvb;
    size_t idx = (size_t)blk * 256 + threadIdx.x;
    const float4 a = ((const float4*)src)[idx * 2 + 0];
    const float4 b = ((const float4*)src)[idx * 2 + 1];
    uint4 o;
    o.x = (u32)f2bf(a.x) | ((u32)f2bf(a.y) << 16);
    o.y = (u32)f2bf(a.z) | ((u32)f2bf(a.w) << 16);
    o.z = (u32)f2bf(b.x) | ((u32)f2bf(b.y) << 16);
    o.w = (u32)f2bf(b.z) | ((u32)f2bf(b.w) << 16);
    ((uint4*)dst)[idx] = o;
}

// ---------------------------------------------------------------------------
// xpart body: per-(batch,chunk) partial column-mean of x -> xpart slot.
// Non-atomic, every slot written (no pre-zero needed; poison-safe).
// Sum of 32 partials == previous atomic xbar exactly (same addends).
// ---------------------------------------------------------------------------
__device__ __forceinline__ void xpart_body(int id, const float* __restrict__ x,
                                           float* __restrict__ xpart) {
    const int b = id >> 5, chunk = id & 31;
    const int tid = threadIdx.x;
    const float* xp = x + (size_t)b * SF + (size_t)chunk * 64 * FDIM;
    float s0 = 0.f, s1 = 0.f;
    for (int r = 0; r < 64; ++r) {
        s0 += xp[(size_t)r * FDIM + tid];
        s1 += xp[(size_t)r * FDIM + tid + 256];
    }
    float* dst = xpart + (size_t)id * FDIM;
    dst[tid]       = s0 * (1.f / 2048.f);
    dst[tid + 256] = s1 * (1.f / 2048.f);
}

// ---------------------------------------------------------------------------
// kNN body (HW-validated r14): exact SET selection via two-level histogram.
// Order-free output (nn used only as boolean mask); set = {33 smallest
// (dist,idx) keys} \ {min key} == stable argsort[1:33].
// ---------------------------------------------------------------------------
__device__ __forceinline__ void knn_body(char* smem, int blk,
                                         const float* __restrict__ coords,
                                         u16* __restrict__ nn_out) {
    u32* chist = (u32*)smem;                  // 64  u32
    u32* fhist = (u32*)(smem + 256);          // 256 u32
    u64* bk    = (u64*)(smem + 1280);         // 64  u64
    u64* wpart = (u64*)(smem + 1792);         // 4   u64
    u32* sc    = (u32*)(smem + 1824);         // 8   u32
    const int b   = blk >> 11;
    const int qi  = blk & (SEQ - 1);
    const int t   = threadIdx.x;
    const int wid = t >> 6, lane = t & 63;
    const size_t qb = (size_t)blk * KNN;

    fhist[t & 255] = 0;
    if (t < 64) chist[t] = 0;
    if (t == 0) { sc[2] = 0; sc[3] = 0; }

    const float* cb = coords + (size_t)b * SEQ * 3;
    const float qx = cb[qi * 3 + 0];
    const float qy = cb[qi * 3 + 1];
    const float qz = cb[qi * 3 + 2];

    float dist[8];
    int   ib[8];
    u64 tmin = ~0ull;
#pragma unroll
    for (int i = 0; i < 8; ++i) {
        int c = i * 256 + t;
        float dx = __fsub_rn(cb[c * 3 + 0], qx);
        float dy = __fsub_rn(cb[c * 3 + 1], qy);
        float dz = __fsub_rn(cb[c * 3 + 2], qz);
        // numpy order: (dx*dx + dy*dy) + dz*dz, no FMA, IEEE sqrt
        float d2 = __fadd_rn(__fadd_rn(__fmul_rn(dx, dx), __fmul_rn(dy, dy)),
                             __fmul_rn(dz, dz));
        dist[i] = __fsqrt_rn(d2);
        ib[i] = (int)(dist[i] * 8192.0f);
        u64 key = (((u64)__float_as_uint(dist[i])) << 32) | (u32)c;
        tmin = min_u64(tmin, key);
    }
    tmin = min_u64(tmin, shfl_xor_u64(tmin, 1));
    tmin = min_u64(tmin, shfl_xor_u64(tmin, 2));
    tmin = min_u64(tmin, shfl_xor_u64(tmin, 4));
    tmin = min_u64(tmin, shfl_xor_u64(tmin, 8));
    tmin = min_u64(tmin, shfl_xor_u64(tmin, 16));
    tmin = min_u64(tmin, shfl_xor_u64(tmin, 32));
    if (lane == 0) wpart[wid] = tmin;
    __syncthreads();                                  // B1

#pragma unroll
    for (int i = 0; i < 8; ++i) atomicAdd(&chist[ib[i] >> 8], 1u);
    const u64 M = min_u64(min_u64(wpart[0], wpart[1]),
                          min_u64(wpart[2], wpart[3]));
    __syncthreads();                                  // B2

    if (t < 64) {
        u32 h = chist[t];
        u32 cum = h;
#pragma unroll
        for (int d = 1; d < 64; d <<= 1) {
            u32 v = (u32)__shfl_up((int)cum, d, 64);
            if (t >= d) cum += v;
        }
        u64 bal = __ballot(cum >= 33);
        int Bc = __ffsll((long long)bal) - 1;
        u32 excl = cum - h;
        u32 base = (u32)__shfl((int)excl, Bc, 64);
        if (t == 0) { sc[0] = (u32)Bc; sc[1] = base; }
    }
    __syncthreads();                                  // B3

    {
        const int Bc = (int)sc[0];
#pragma unroll
        for (int i = 0; i < 8; ++i)
            if ((ib[i] >> 8) == Bc) atomicAdd(&fhist[ib[i] & 255], 1u);
    }
    __syncthreads();                                  // B4

    if (t < 64) {
        const u32 Bc = sc[0], base = sc[1];
        u32 f0 = fhist[t * 4 + 0], f1 = fhist[t * 4 + 1];
        u32 f2 = fhist[t * 4 + 2], f3 = fhist[t * 4 + 3];
        u32 s = f0 + f1 + f2 + f3;
        u32 cum = s;
#pragma unroll
        for (int d = 1; d < 64; d <<= 1) {
            u32 v = (u32)__shfl_up((int)cum, d, 64);
            if (t >= d) cum += v;
        }
        u32 E = base + (cum - s);
        u32 c0 = E + f0, c1 = c0 + f1, c2 = c1 + f2, c3 = c2 + f3;
        u64 bal = __ballot(c3 >= 33);
        int L = __ffsll((long long)bal) - 1;
        if (t == L) {
            int j = (c0 >= 33) ? 0 : (c1 >= 33) ? 1 : (c2 >= 33) ? 2 : 3;
            sc[4] = (Bc << 8) | (u32)(t * 4 + j);     // IBT
        }
    }
    __syncthreads();                                  // B5

    {
        const int ibt = (int)sc[4];
#pragma unroll
        for (int i = 0; i < 8; ++i) {
            int c = i * 256 + t;
            u64 key = (((u64)__float_as_uint(dist[i])) << 32) | (u32)c;
            if (ib[i] < ibt) {
                if (key != M) {
                    u32 pos = atomicAdd(&sc[2], 1u);
                    nn_out[qb + pos] = (u16)c;
                }
            } else if (ib[i] == ibt) {
                u32 bp = atomicAdd(&sc[3], 1u);
                if (bp < 64) bk[bp] = key;
            }
        }
    }
    __syncthreads();                                  // B6

    if (t < 64) {
        const u32 m = sc[2];
        const int n = (int)min(sc[3], 64u);
        const int need = 32 - (int)m;
        u64 k = (t < n) ? bk[t] : ~0ull;
        if (k == M) k = ~0ull;
#pragma unroll 1
        for (int r = 0; r < need; ++r) {
            u64 g = k;
            g = min_u64(g, shfl_xor_u64(g, 1));
            g = min_u64(g, shfl_xor_u64(g, 2));
            g = min_u64(g, shfl_xor_u64(g, 4));
            g = min_u64(g, shfl_xor_u64(g, 8));
            g = min_u64(g, shfl_xor_u64(g, 16));
            g = min_u64(g, shfl_xor_u64(g, 32));
            if (k == g) {
                nn_out[qb + m + r] = (u16)(g & 0x7FF);
                k = ~0ull;
            }
        }
    }
}

// ---------------------------------------------------------------------------
// FUSED dispatch 1: cast + xpart + knn (r17-validated pairing; no gemm).
// ---------------------------------------------------------------------------
__global__ __launch_bounds__(256) void fused_ck(const float* __restrict__ x,
                                                const float* __restrict__ wq,
                                                const float* __restrict__ wk,
                                                const float* __restrict__ wv,
                                                bf16_t* __restrict__ xb,
                                                bf16_t* __restrict__ wqb,
                                                bf16_t* __restrict__ wkb,
                                                bf16_t* __restrict__ wvb,
                                                const float* __restrict__ coords,
                                                u16* __restrict__ nn_out,
                                                float* __restrict__ xpart) {
    __shared__ __align__(16) char smem[1856];   // knn scratch only
    const int bid = blockIdx.x;
    if (bid < CAST_NB) {
        cast_body(bid, x, wq, wk, wv, xb, wqb, wkb, wvb);
    } else if (bid < CAST_NB + XPART_NB) {
        xpart_body(bid - CAST_NB, x, xpart);
    } else {
        knn_body(smem, bid - CAST_NB - XPART_NB, coords, nn_out);
    }
}

// ---------------------------------------------------------------------------
// Dispatch 2: GEMM (r15 HW-validated body) + metric tail slab (z==3).
// z=0 -> q (fp32 to d_out); z=1,2 -> k,v (bf16 to ws); z=3 -> metric
// (8 real blocks reduce xpart in LDS then dot with fp32 Wk; 248 no-ops).
// ---------------------------------------------------------------------------
__global__ __launch_bounds__(256) void gemm_mfma(const bf16_t* __restrict__ xb,
                                                 const bf16_t* __restrict__ wqb,
                                                 const bf16_t* __restrict__ wkb,
                                                 const bf16_t* __restrict__ wvb,
                                                 float* __restrict__ qout,
                                                 bf16_t* __restrict__ kvout,
                                                 const float* __restrict__ xpart,
                                                 const float* __restrict__ Wkf,
                                                 float* __restrict__ metric) {
    __shared__ __align__(16) bf16_t As[128 * 32];
    __shared__ __align__(16) bf16_t Bs[128 * 32];
    const int z = blockIdx.z;
    const int tid  = threadIdx.x;

    if (z == 3) {                         // ---- metric tail ----
        const int id = blockIdx.y * 4 + blockIdx.x;    // 0..255
        if (id >= 8) return;
        float* xbarL = (float*)As;        // 2 KB of the 16 KB buffer
        const int b = id >> 1;
        float a0 = 0.f, a1 = 0.f;
#pragma unroll 4
        for (int c = 0; c < 32; ++c) {
            const float* xp = xpart + (size_t)((b << 5) | c) * FDIM;
            a0 += xp[tid];
            a1 += xp[tid + 256];
        }
        xbarL[tid] = a0; xbarL[tid + 256] = a1;
        __syncthreads();
        const int f = ((id & 1) << 8) | tid;
        const float* wr = Wkf + (size_t)f * FDIM;
        float acc = 0.f;
#pragma unroll 4
        for (int kk = 0; kk < FDIM; kk += 4) {
            float4 wv = *(const float4*)(wr + kk);
            acc += xbarL[kk + 0] * wv.x + xbarL[kk + 1] * wv.y
                 + xbarL[kk + 2] * wv.z + xbarL[kk + 3] * wv.w;
        }
        metric[(b << 9) | f] = acc;
        return;
    }

    const bf16_t* W = (z == 0) ? wqb : (z == 1) ? wkb : wvb;
    const int wid  = tid >> 6, lane = tid & 63;
    const int m16  = lane & 15, quad = lane >> 4;
    const int wm   = (wid & 1) * 64;
    const int wn   = (wid >> 1) * 64;
    const int m0   = blockIdx.y * 128;
    const int n0   = blockIdx.x * 128;

    const int sr = tid >> 2, sc = (tid & 3) * 8;
    const bf16_t* agp = xb + (size_t)(m0 + sr) * FDIM + sc;
    const bf16_t* bgp = W  + (size_t)(n0 + sr) * FDIM + sc;

    f32x4 acc[4][4];
#pragma unroll
    for (int i = 0; i < 4; ++i)
#pragma unroll
        for (int j = 0; j < 4; ++j) acc[i][j] = (f32x4){0.f, 0.f, 0.f, 0.f};

#pragma unroll 1
    for (int k0 = 0; k0 < FDIM; k0 += 32) {
        uint4 a0 = *(const uint4*)(agp + k0);
        uint4 a1 = *(const uint4*)(agp + (size_t)64 * FDIM + k0);
        uint4 b0 = *(const uint4*)(bgp + k0);
        uint4 b1 = *(const uint4*)(bgp + (size_t)64 * FDIM + k0);
        __syncthreads();
        *(uint4*)(As + sr * 32 + sc)        = a0;
        *(uint4*)(As + (sr + 64) * 32 + sc) = a1;
        *(uint4*)(Bs + sr * 32 + sc)        = b0;
        *(uint4*)(Bs + (sr + 64) * 32 + sc) = b1;
        __syncthreads();

        short8 af[4], bfr[4];
#pragma unroll
        for (int i = 0; i < 4; ++i)
            af[i] = *(const short8*)(As + (wm + i * 16 + m16) * 32 + quad * 8);
#pragma unroll
        for (int j = 0; j < 4; ++j)
            bfr[j] = *(const short8*)(Bs + (wn + j * 16 + m16) * 32 + quad * 8);
#pragma unroll
        for (int i = 0; i < 4; ++i)
#pragma unroll
            for (int j = 0; j < 4; ++j)
                acc[i][j] = __builtin_amdgcn_mfma_f32_16x16x32_bf16(af[i], bfr[j],
                                                                    acc[i][j], 0, 0, 0);
    }

    if (z == 0) {
#pragma unroll
        for (int i = 0; i < 4; ++i) {
            const int rowb = m0 + wm + i * 16 + quad * 4;
#pragma unroll
            for (int r = 0; r < 4; ++r) {
                float* orow = qout + (size_t)(rowb + r) * FDIM + n0 + wn + m16;
                orow[ 0] = acc[i][0][r]; orow[16] = acc[i][1][r];
                orow[32] = acc[i][2][r]; orow[48] = acc[i][3][r];
            }
        }
    } else {
        bf16_t* base = kvout + (size_t)(z - 1) * BSF;
#pragma unroll
        for (int i = 0; i < 4; ++i) {
            const int rowb = m0 + wm + i * 16 + quad * 4;
#pragma unroll
            for (int r = 0; r < 4; ++r) {
                bf16_t* orow = base + (size_t)(rowb + r) * FDIM + n0 + wn + m16;
                orow[ 0] = f2bf(acc[i][0][r]); orow[16] = f2bf(acc[i][1][r]);
                orow[32] = f2bf(acc[i][2][r]); orow[48] = f2bf(acc[i][3][r]);
            }
        }
    }
}

// ---------------------------------------------------------------------------
// Dispatch 3: Attention v4 — r15 HW-validated kernel VERBATIM (barrier-free,
// one wave per (q,h), single gather epoch, XCD swizzle). Standalone again
// (r17 lesson: fusing the metric tail cost ~17 µs via an occupancy drop).
// ---------------------------------------------------------------------------
__global__ __launch_bounds__(256, 8) void attn_kernel(const bf16_t* __restrict__ kv,
                                                      const u16* __restrict__ nn,
                                                      float* __restrict__ out) {
    __shared__ float qsl[4][64];                          // 1 KB, per-wave slot
    const int i   = blockIdx.x;                           // 0..16383
    const int b   = (i & 7) >> 1;                         // XCD pair -> batch
    const int jb  = ((i >> 3) << 1) | (i & 1);            // 0..4095, bijective
    const int tid = threadIdx.x;
    const int wid = tid >> 6, lane = tid & 63;
    const int gid = (jb << 2) | wid;                      // 0..16383 per batch
    const int qi  = gid >> 3, h = gid & 7;
    const int blk = (b << 11) | qi;

    int sreg = 0;
    if (lane < KNN) sreg = (int)nn[(size_t)blk * KNN + lane] & (SEQ - 1);
    qsl[wid][lane] = out[(size_t)blk * FDIM + h * HDIM + lane];   // own q slice
    __asm__ volatile("s_waitcnt lgkmcnt(0)" ::: "memory");
    __builtin_amdgcn_wave_barrier();

    const int j = lane & 31, half = lane >> 5;
    const int rowj = __shfl(sreg, j, 64);
    const bf16_t* kreg = kv + ((size_t)((b << 11) + rowj)) * FDIM + h * HDIM + half * 32;
    uint4 k0 = *(const uint4*)(kreg + 0);
    uint4 k1 = *(const uint4*)(kreg + 8);
    uint4 k2 = *(const uint4*)(kreg + 16);
    uint4 k3 = *(const uint4*)(kreg + 24);

    const int g = lane >> 4, l = lane & 15;
    const bf16_t* vbase = kv + BSF + ((size_t)(b << 11)) * FDIM + h * HDIM + l * 4;
    uint2 vv[8];
#pragma unroll
    for (int t2 = 0; t2 < 8; ++t2) {
        const int row = __shfl(sreg, (g << 3) | t2, 64);
        vv[t2] = *(const uint2*)(vbase + (size_t)row * FDIM);   // 4 bf16
    }

    const float* qp = &qsl[wid][half * 32];
    float acc = 0.f;
    {
        float f0, f1, f2, f3, f4, f5, f6, f7;
        bf2x2(k0.x, f0, f1); bf2x2(k0.y, f2, f3);
        bf2x2(k0.z, f4, f5); bf2x2(k0.w, f6, f7);
        acc += qp[0] * f0 + qp[1] * f1 + qp[2] * f2 + qp[3] * f3
             + qp[4] * f4 + qp[5] * f5 + qp[6] * f6 + qp[7] * f7;
        bf2x2(k1.x, f0, f1); bf2x2(k1.y, f2, f3);
        bf2x2(k1.z, f4, f5); bf2x2(k1.w, f6, f7);
        acc += qp[8] * f0 + qp[9] * f1 + qp[10] * f2 + qp[11] * f3
             + qp[12] * f4 + qp[13] * f5 + qp[14] * f6 + qp[15] * f7;
        bf2x2(k2.x, f0, f1); bf2x2(k2.y, f2, f3);
        bf2x2(k2.z, f4, f5); bf2x2(k2.w, f6, f7);
        acc += qp[16] * f0 + qp[17] * f1 + qp[18] * f2 + qp[19] * f3
             + qp[20] * f4 + qp[21] * f5 + qp[22] * f6 + qp[23] * f7;
        bf2x2(k3.x, f0, f1); bf2x2(k3.y, f2, f3);
        bf2x2(k3.z, f4, f5); bf2x2(k3.w, f6, f7);
        acc += qp[24] * f0 + qp[25] * f1 + qp[26] * f2 + qp[27] * f3
             + qp[28] * f4 + qp[29] * f5 + qp[30] * f6 + qp[31] * f7;
    }
    acc += __shfl_xor(acc, 32, 64);
    float s = acc * 0.125f;                 // 1/sqrt(64)
    float m = s;
    m = fmaxf(m, __shfl_xor(m, 1, 64));
    m = fmaxf(m, __shfl_xor(m, 2, 64));
    m = fmaxf(m, __shfl_xor(m, 4, 64));
    m = fmaxf(m, __shfl_xor(m, 8, 64));
    m = fmaxf(m, __shfl_xor(m, 16, 64));
    float e = __expf(s - m);
    float sum = e;
    sum += __shfl_xor(sum, 1, 64);
    sum += __shfl_xor(sum, 2, 64);
    sum += __shfl_xor(sum, 4, 64);
    sum += __shfl_xor(sum, 8, 64);
    sum += __shfl_xor(sum, 16, 64);
    float w = e / sum;                      // valid per j on lanes j and j+32

    float o0 = 0.f, o1 = 0.f, o2 = 0.f, o3 = 0.f;
#pragma unroll
    for (int t2 = 0; t2 < 8; ++t2) {
        const float wj = __shfl(w, (g << 3) | t2, 64);
        float f0, f1, f2, f3;
        bf2x2(vv[t2].x, f0, f1); bf2x2(vv[t2].y, f2, f3);
        o0 += wj * f0; o1 += wj * f1; o2 += wj * f2; o3 += wj * f3;
    }
    o0 += __shfl_xor(o0, 16, 64); o0 += __shfl_xor(o0, 32, 64);
    o1 += __shfl_xor(o1, 16, 64); o1 += __shfl_xor(o1, 32, 64);
    o2 += __shfl_xor(o2, 16, 64); o2 += __shfl_xor(o2, 32, 64);
    o3 += __shfl_xor(o3, 16, 64); o3 += __shfl_xor(o3, 32, 64);
    if (g == 0) {
        float4 ov = make_float4(o0, o1, o2, o3);
        *(float4*)(out + (size_t)blk * FDIM + h * HDIM + l * 4) = ov;
    }
}

// ---------------------------------------------------------------------------
extern "C" void kernel_launch(void* const* d_in, const int* in_sizes, int n_in,
                              void* d_out, int out_size, void* d_ws, size_t ws_size,
                              hipStream_t stream) {
    const float* x      = (const float*)d_in[0];
    const float* coords = (const float*)d_in[1];
    const float* Wq     = (const float*)d_in[2];
    const float* Wk     = (const float*)d_in[3];
    const float* Wv     = (const float*)d_in[4];
    float* out    = (float*)d_out;
    float* metric = out + BSF;

    // ws layout (~26.3 MiB):
    //   xb bf16 BSF (8 MiB) | wqb/wkb/wvb bf16 (1.5 MiB) | kv bf16 2*BSF (16 MiB)
    //   | nn u16 (0.5 MiB) | xpart f32 128*512 (256 KiB)
    char* p = (char*)d_ws;
    bf16_t* xb    = (bf16_t*)p;                      p += BSF * sizeof(bf16_t);
    bf16_t* wqb   = (bf16_t*)p;                      p += (size_t)FDIM * FDIM * sizeof(bf16_t);
    bf16_t* wkb   = (bf16_t*)p;                      p += (size_t)FDIM * FDIM * sizeof(bf16_t);
    bf16_t* wvb   = (bf16_t*)p;                      p += (size_t)FDIM * FDIM * sizeof(bf16_t);
    bf16_t* kv    = (bf16_t*)p;                      p += 2 * BSF * sizeof(bf16_t);
    u16*    nn    = (u16*)p;                         p += (size_t)BATCH * SEQ * KNN * sizeof(u16);
    float*  xpart = (float*)p;

    // 1) cast + xpart + knn (no memset needed: xpart fully written)
    fused_ck<<<CAST_NB + XPART_NB + BATCH * SEQ, 256, 0, stream>>>(
        x, Wq, Wk, Wv, xb, wqb, wkb, wvb, coords, nn, xpart);

    // 2) gemm (q -> d_out fp32, k/v -> ws bf16) + metric tail (z==3)
    gemm_mfma<<<dim3(FDIM / 128, (BATCH * SEQ) / 128, 4), 256, 0, stream>>>(
        xb, wqb, wkb, wvb, out, kv, xpart, Wk, metric);

    // 3) attention standalone (r15 form)
    attn_kernel<<<BATCH * SEQ * NHEAD / 4, 256, 0, stream>>>(kv, nn, out);
}